// Round 23
// baseline (250.819 us; speedup 1.0000x reference)
//
#include <hip/hip_runtime.h>

typedef _Float16 h8 __attribute__((ext_vector_type(8)));
typedef unsigned short u16x8 __attribute__((ext_vector_type(8)));
typedef float   f32x16 __attribute__((ext_vector_type(16)));

constexpr int NSUB  = 8;
constexpr int NCODE = 256;
constexpr int SDIM  = 96;
constexpr int EMB   = NSUB * SDIM;          // 768
constexpr float C_SHIFT = 192.0f;   // harmless shift baked into c2 (cancels in gaps)
constexpr float THR = 0.03f;        // 10 sigma of fp16 gap-error (sigma ~ 3e-3)

// ws layout: fp16 frags | c2 | counter | trigger list
constexpr size_t WS_FRAG_BYTES = (size_t)NSUB * 3072 * 16;       // 393216
constexpr size_t C2_BYTES      = (size_t)NSUB * NCODE * 4;       // 8192
constexpr size_t CNT_OFF       = WS_FRAG_BYTES + C2_BYTES;       // 401408
constexpr size_t LIST_OFF      = CNT_OFF + 16;                   // 401424
constexpr size_t WS_NEEDED     = LIST_OFF + 65536 * 4;           // >= 64k entries

// -------- pre-kernel: pack codebook into fp16 32x32 A-fragments + c2 --------
// unit u = t*6+s, lane l: code = t*32+(l&31), k = s*16+(l>>5)*8+j, val = fp16(-c).
// wsc2 = 0.5*||c||^2 + C_SHIFT (fp64).
__global__ __launch_bounds__(256) void pq_prep_h(const float* __restrict__ cb,
                                                 unsigned short* __restrict__ wsf,
                                                 float* __restrict__ wsc2)
{
    const int m   = (int)blockIdx.x;
    const int tid = (int)threadIdx.x;
    {
        const float* c = cb + ((size_t)m * NCODE + tid) * SDIM;
        double s = 0.0;
        for (int k = 0; k < SDIM; ++k) { double v = (double)c[k]; s += v * v; }
        wsc2[m * NCODE + tid] = (float)(0.5 * s + (double)C_SHIFT);
    }
    for (int i = 0; i < 12; ++i) {
        int idx = i * 256 + tid;        // [0, 3072) = u*64 + l
        int l   = idx & 63;
        int u   = idx >> 6;             // [0, 48) = t*6 + s
        int s   = u % 6;
        int t   = u / 6;
        int code = t * 32 + (l & 31);
        int k0   = s * 16 + (l >> 5) * 8;
        const float* src = cb + (size_t)m * NCODE * SDIM + (size_t)code * SDIM + k0;
        u16x8 o;
        #pragma unroll
        for (int j = 0; j < 8; ++j) {
            _Float16 hv = (_Float16)(-src[j]);   // RNE
            o[j] = __builtin_bit_cast(unsigned short, hv);
        }
        *(u16x8*)(wsf + ((size_t)m * 3072 + idx) * 8) = o;
    }
}

// ------ main: one wave owns (m, 32 rows). NO LDS/barriers (R22 shape,     ------
// ------ 166us standalone, VGPR 56). fp16 single-pass MFMA + top-2 float   ------
// ------ scan; near-ties appended to repair list (no inline fp64).         ------
__global__ __launch_bounds__(128) void pq_mfma21(
    const float* __restrict__ emb,
    const float* __restrict__ cb,
    const unsigned short* __restrict__ wsf,
    const float* __restrict__ wsc2,
    float* __restrict__ out,
    unsigned* __restrict__ gcnt,
    unsigned* __restrict__ glist,
    unsigned cap,
    int nrows,
    int rowblks)
{
    const int tid  = (int)threadIdx.x;
    const int lane = tid & 63;
    const int hib  = lane >> 5;
    const int m    = (int)blockIdx.x & 7;               // XCD-pinned subspace
    const int rb   = ((int)blockIdx.x >> 3) * 2 + (tid >> 6);
    if (rb >= rowblks) return;
    const int row0 = rb * 32;

    const unsigned short* wb = wsf + (size_t)m * 3072 * 8;
    const float* c2p = wsc2 + m * NCODE;

    // ---- x fragments (B operand, fp16): lane l = row row0+(l&31), dims hib*8+s*16+j ----
    h8 xh[6];
    {
        int r = row0 + (lane & 31);
        if (r >= nrows) r = nrows - 1;
        const float* xr = emb + (size_t)r * EMB + m * SDIM + hib * 8;
        #pragma unroll
        for (int s = 0; s < 6; ++s) {
            float4 v0 = *(const float4*)(xr + s * 16);
            float4 v1 = *(const float4*)(xr + s * 16 + 4);
            float v[8] = { v0.x, v0.y, v0.z, v0.w, v1.x, v1.y, v1.z, v1.w };
            #pragma unroll
            for (int j = 0; j < 8; ++j) xh[s][j] = (_Float16)v[j];
        }
    }

    // ---- 4 t-pairs: acc init from c2, 12 MFMA, top-2 scan (code-ascending) ----
    float b1 = 3.4e38f, b2 = 3.4e38f;
    int   i1 = 1 << 30;
    #pragma unroll 1
    for (int p = 0; p < 4; ++p) {
        const int t0 = p * 2, t1 = t0 + 1;
        f32x16 a0, a1;
        #pragma unroll
        for (int rq = 0; rq < 4; ++rq) {
            float4 q0 = *(const float4*)(c2p + t0 * 32 + rq * 8 + hib * 4);
            float4 q1 = *(const float4*)(c2p + t1 * 32 + rq * 8 + hib * 4);
            a0[rq*4+0]=q0.x; a0[rq*4+1]=q0.y; a0[rq*4+2]=q0.z; a0[rq*4+3]=q0.w;
            a1[rq*4+0]=q1.x; a1[rq*4+1]=q1.y; a1[rq*4+2]=q1.z; a1[rq*4+3]=q1.w;
        }
        __builtin_amdgcn_s_setprio(1);
        #pragma unroll
        for (int s = 0; s < 6; ++s) {
            h8 c0 = *(const h8*)(wb + (size_t)((t0 * 6 + s) * 64 + lane) * 8);
            h8 c1 = *(const h8*)(wb + (size_t)((t1 * 6 + s) * 64 + lane) * 8);
            a0 = __builtin_amdgcn_mfma_f32_32x32x16_f16(c0, xh[s], a0, 0, 0, 0);
            a1 = __builtin_amdgcn_mfma_f32_32x32x16_f16(c1, xh[s], a1, 0, 0, 0);
        }
        __builtin_amdgcn_s_setprio(0);
        // top-2 serial scan, ascending code order per lane (first-min tie rule)
        #pragma unroll
        for (int r = 0; r < 16; ++r) {
            float sv = a0[r];
            int   kv = t0 * 32 + (r & 3) + 8 * (r >> 2) + hib * 4;
            if (sv < b1)      { b2 = b1; b1 = sv; i1 = kv; }
            else if (sv < b2) { b2 = sv; }
        }
        #pragma unroll
        for (int r = 0; r < 16; ++r) {
            float sv = a1[r];
            int   kv = t1 * 32 + (r & 3) + 8 * (r >> 2) + hib * 4;
            if (sv < b1)      { b2 = b1; b1 = sv; i1 = kv; }
            else if (sv < b2) { b2 = sv; }
        }
    }
    {   // merge lane^32 partner (index-aware winner; b2 = min of the rest)
        float ob1 = __shfl_xor(b1, 32);
        int   oi1 = __shfl_xor(i1, 32);
        float ob2 = __shfl_xor(b2, 32);
        bool o_better = (ob1 < b1) || (ob1 == b1 && oi1 < i1);
        float loser = o_better ? b1 : ob1;
        if (o_better) { b1 = ob1; i1 = oi1; }
        b2 = fminf(fminf(b2, ob2), loser);
    }

    // ---- near-tie: append to repair list (exact fp64 rescan in pq_repair2) ----
    {
        int grow = row0 + (lane & 31);
        if (lane < 32 && grow < nrows && (b2 - b1 < THR)) {
            unsigned pos = atomicAdd(gcnt, 1u);
            if (pos < cap) glist[pos] = (unsigned)grow | ((unsigned)m << 20);
        }
    }

    // ---- gather + coalesced write-out (provisional for triggered rows) ----
    #pragma unroll
    for (int ii = 0; ii < 12; ++ii) {
        int Q = ii * 64 + lane;                 // 768 = 32 rows x 24 float4
        int r = Q / 24, f = Q % 24;
        int grow = row0 + r;
        int k = __shfl(i1, r);                  // winner held by lane r (<32)
        if (grow < nrows) {
            float4 v = *(const float4*)(cb + ((size_t)m * NCODE + k) * SDIM + f * 4);
            *(float4*)(out + (size_t)grow * EMB + m * SDIM + f * 4) = v;
        }
    }
}

// ------ repair v2: wave per listed row; lane-per-dim layout (COALESCED).   ------
// ------ x loaded once per row; per iter 2 codes (one half-wave each): one  ------
// ------ coalesced float4 load + fp64 partials + 5-step butterfly. Exact.   ------
__global__ __launch_bounds__(256) void pq_repair2(
    const float* __restrict__ emb,
    const float* __restrict__ cb,
    float* __restrict__ out,
    const unsigned* __restrict__ gcnt,
    const unsigned* __restrict__ glist,
    unsigned cap)
{
    const int tid  = (int)threadIdx.x;
    const int lane = tid & 63;
    const int hl   = lane & 31;                 // position within half-wave
    const int hib  = lane >> 5;                 // 0: even codes, 1: odd codes
    const int dch  = hl < 24 ? hl : 23;         // dim chunk (lanes 24-31 masked)
    const bool act = hl < 24;
    const unsigned wv = (unsigned)blockIdx.x * 4u + (unsigned)(tid >> 6);
    unsigned n = *gcnt; if (n > cap) n = cap;

    for (unsigned j = wv; j < n; j += 4096u) {
        unsigned e = glist[j];
        int grow = (int)(e & 0xFFFFFu);
        int m    = (int)(e >> 20);
        const float* xr  = emb + (size_t)grow * EMB + m * SDIM;
        const float* cbm = cb + (size_t)m * NCODE * SDIM;

        float4 xv = *(const float4*)(xr + dch * 4);    // this lane's 4 dims, once

        double bd = 1e300; int bc = NCODE;
        #pragma unroll 1
        for (int c = 0; c < NCODE; c += 2) {
            const int code = c + hib;                  // lo half: c, hi half: c+1
            float4 cc = *(const float4*)(cbm + (size_t)code * SDIM + dch * 4);
            double par = 0.0;
            if (act) {
                double d0 = (double)xv.x - (double)cc.x;
                double d1 = (double)xv.y - (double)cc.y;
                double d2 = (double)xv.z - (double)cc.z;
                double d3 = (double)xv.w - (double)cc.w;
                par = d0*d0 + d1*d1 + d2*d2 + d3*d3;
            }
            // butterfly sum within the 32-lane half (all lanes end with the total)
            #pragma unroll
            for (int off = 16; off > 0; off >>= 1)
                par += __shfl_xor(par, off);
            // ascending c per half => strict < keeps first-min of this parity
            if (par < bd) { bd = par; bc = code; }
        }
        {   // cross-half merge, index-aware (numpy tie rule)
            double od = __shfl_xor(bd, 32);
            int    oc = __shfl_xor(bc, 32);
            if (od < bd || (od == bd && oc < bc)) { bd = od; bc = oc; }
        }
        if (lane < 24) {
            float4 v = *(const float4*)(cbm + (size_t)bc * SDIM + lane * 4);
            *(float4*)(out + (size_t)grow * EMB + m * SDIM + lane * 4) = v;
        }
    }
}

// ---------------- fallback (round-2 kernel, validated) ----------------
__global__ __launch_bounds__(256) void pq_argmin_kernel(
    const float* __restrict__ emb, const float* __restrict__ cb,
    float* __restrict__ out, int nrows)
{
    const int m   = (int)(blockIdx.x & 7);
    const int row = (int)(blockIdx.x >> 3) * 256 + (int)threadIdx.x;
    const float* __restrict__ cbm = cb + (size_t)m * (NCODE * SDIM);
    __shared__ float half_c2[NCODE];
    {
        const int k = (int)threadIdx.x;
        const float* c = cbm + k * SDIM;
        float s = 0.f;
        #pragma unroll
        for (int i = 0; i < SDIM; i += 4) {
            const float4 v = *reinterpret_cast<const float4*>(c + i);
            s = fmaf(v.x, v.x, s); s = fmaf(v.y, v.y, s);
            s = fmaf(v.z, v.z, s); s = fmaf(v.w, v.w, s);
        }
        half_c2[k] = 0.5f * s;
    }
    __syncthreads();
    if (row >= nrows) return;
    float x[SDIM];
    {
        const float* xr = emb + (size_t)row * EMB + m * SDIM;
        #pragma unroll
        for (int i = 0; i < SDIM; i += 4) {
            const float4 v = *reinterpret_cast<const float4*>(xr + i);
            x[i+0] = v.x; x[i+1] = v.y; x[i+2] = v.z; x[i+3] = v.w;
        }
    }
    float best = 3.4e38f, best2 = 3.4e38f;
    int bestk = 0, bestk2 = 0;
    #pragma unroll 1
    for (int k = 0; k < NCODE; k += 4) {
        const float* c0 = cbm + (k + 0) * SDIM;
        const float* c1 = cbm + (k + 1) * SDIM;
        const float* c2 = cbm + (k + 2) * SDIM;
        const float* c3 = cbm + (k + 3) * SDIM;
        float a0 = 0.f, a1 = 0.f, a2 = 0.f, a3 = 0.f;
        #pragma unroll
        for (int i = 0; i < SDIM; i += 4) {
            const float4 v0 = *reinterpret_cast<const float4*>(c0 + i);
            const float4 v1 = *reinterpret_cast<const float4*>(c1 + i);
            const float4 v2 = *reinterpret_cast<const float4*>(c2 + i);
            const float4 v3 = *reinterpret_cast<const float4*>(c3 + i);
            a0 = fmaf(x[i+0], v0.x, a0); a0 = fmaf(x[i+1], v0.y, a0);
            a0 = fmaf(x[i+2], v0.z, a0); a0 = fmaf(x[i+3], v0.w, a0);
            a1 = fmaf(x[i+0], v1.x, a1); a1 = fmaf(x[i+1], v1.y, a1);
            a1 = fmaf(x[i+2], v1.z, a1); a1 = fmaf(x[i+3], v1.w, a1);
            a2 = fmaf(x[i+0], v2.x, a2); a2 = fmaf(x[i+1], v2.y, a2);
            a2 = fmaf(x[i+2], v2.z, a2); a2 = fmaf(x[i+3], v2.w, a2);
            a3 = fmaf(x[i+0], v3.x, a3); a3 = fmaf(x[i+1], v3.y, a3);
            a3 = fmaf(x[i+2], v3.z, a3); a3 = fmaf(x[i+3], v3.w, a3);
        }
        const float s[4] = { half_c2[k+0] - a0, half_c2[k+1] - a1,
                             half_c2[k+2] - a2, half_c2[k+3] - a3 };
        #pragma unroll
        for (int j = 0; j < 4; ++j) {
            if (s[j] < best)       { best2 = best; bestk2 = bestk; best = s[j]; bestk = k + j; }
            else if (s[j] < best2) { best2 = s[j]; bestk2 = k + j; }
        }
    }
    if (best2 - best < 0.02f) {
        const float* ca = cbm + bestk  * SDIM;
        const float* cbv = cbm + bestk2 * SDIM;
        double da = 0.0, db = 0.0;
        for (int i = 0; i < SDIM; ++i) {
            const double ea = (double)x[i] - (double)ca[i];
            const double eb = (double)x[i] - (double)cbv[i];
            da += ea * ea; db += eb * eb;
        }
        if (db < da || (db == da && bestk2 < bestk)) bestk = bestk2;
    }
    const float* cbest = cbm + bestk * SDIM;
    float* o = out + (size_t)row * EMB + m * SDIM;
    #pragma unroll
    for (int i = 0; i < SDIM; i += 4)
        *reinterpret_cast<float4*>(o + i) = *reinterpret_cast<const float4*>(cbest + i);
}

extern "C" void kernel_launch(void* const* d_in, const int* in_sizes, int n_in,
                              void* d_out, int out_size, void* d_ws, size_t ws_size,
                              hipStream_t stream) {
    const float* emb = (const float*)d_in[0];
    const float* cb  = (const float*)d_in[1];
    float* out = (float*)d_out;
    const int nrows = in_sizes[0] / EMB;    // 65536

    if (ws_size < WS_NEEDED) {
        const int rowBlocks = (nrows + 255) / 256;
        pq_argmin_kernel<<<dim3(rowBlocks * NSUB), dim3(256), 0, stream>>>(emb, cb, out, nrows);
        return;
    }

    unsigned short* wsf = (unsigned short*)d_ws;
    float*    wsc2  = (float*)((char*)d_ws + WS_FRAG_BYTES);
    unsigned* gcnt  = (unsigned*)((char*)d_ws + CNT_OFF);
    unsigned* glist = (unsigned*)((char*)d_ws + LIST_OFF);
    unsigned  cap   = (unsigned)((ws_size - LIST_OFF) / 4);

    hipMemsetAsync(gcnt, 0, 4, stream);
    pq_prep_h<<<dim3(NSUB), dim3(256), 0, stream>>>(cb, wsf, wsc2);

    const int rowblks = (nrows + 31) / 32;              // 2048
    const int nb      = ((rowblks + 1) / 2) * NSUB;     // 8192 blocks of 128
    pq_mfma21<<<dim3(nb), dim3(128), 0, stream>>>(emb, cb, wsf, wsc2, out,
                                                  gcnt, glist, cap, nrows, rowblks);
    pq_repair2<<<dim3(1024), dim3(256), 0, stream>>>(emb, cb, out, gcnt, glist, cap);
}

// Round 24
// 197.597 us; speedup vs baseline: 1.2693x; 1.2693x over previous
//
#include <hip/hip_runtime.h>

typedef _Float16 h8 __attribute__((ext_vector_type(8)));
typedef unsigned short u16x8 __attribute__((ext_vector_type(8)));
typedef float   f32x16 __attribute__((ext_vector_type(16)));

constexpr int NSUB  = 8;
constexpr int NCODE = 256;
constexpr int SDIM  = 96;
constexpr int EMB   = NSUB * SDIM;          // 768
constexpr float C_SHIFT = 192.0f;   // harmless shift baked into c2 (cancels in gaps)
constexpr float THR = 0.04f;        // R19/R21-validated top-3 guard threshold

// ws layout: fp16 frags | c2 | counter | trigger list (uint2)
constexpr size_t WS_FRAG_BYTES = (size_t)NSUB * 3072 * 16;       // 393216
constexpr size_t C2_BYTES      = (size_t)NSUB * NCODE * 4;       // 8192
constexpr size_t CNT_OFF       = WS_FRAG_BYTES + C2_BYTES;       // 401408
constexpr size_t LIST_OFF      = CNT_OFF + 16;                   // 401424 (8-aligned)
constexpr size_t WS_NEEDED     = LIST_OFF + 49000 * 8;           // 793424 < proven ws floor

// -------- pre-kernel: pack codebook into fp16 32x32 A-fragments + c2 --------
// unit u = t*6+s, lane l: code = t*32+(l&31), k = s*16+(l>>5)*8+j, val = fp16(-c).
// wsc2 = 0.5*||c||^2 + C_SHIFT (fp64).
__global__ __launch_bounds__(256) void pq_prep_h(const float* __restrict__ cb,
                                                 unsigned short* __restrict__ wsf,
                                                 float* __restrict__ wsc2)
{
    const int m   = (int)blockIdx.x;
    const int tid = (int)threadIdx.x;
    {
        const float* c = cb + ((size_t)m * NCODE + tid) * SDIM;
        double s = 0.0;
        for (int k = 0; k < SDIM; ++k) { double v = (double)c[k]; s += v * v; }
        wsc2[m * NCODE + tid] = (float)(0.5 * s + (double)C_SHIFT);
    }
    for (int i = 0; i < 12; ++i) {
        int idx = i * 256 + tid;        // [0, 3072) = u*64 + l
        int l   = idx & 63;
        int u   = idx >> 6;             // [0, 48) = t*6 + s
        int s   = u % 6;
        int t   = u / 6;
        int code = t * 32 + (l & 31);
        int k0   = s * 16 + (l >> 5) * 8;
        const float* src = cb + (size_t)m * NCODE * SDIM + (size_t)code * SDIM + k0;
        u16x8 o;
        #pragma unroll
        for (int j = 0; j < 8; ++j) {
            _Float16 hv = (_Float16)(-src[j]);   // RNE
            o[j] = __builtin_bit_cast(unsigned short, hv);
        }
        *(u16x8*)(wsf + ((size_t)m * 3072 + idx) * 8) = o;
    }
}

// ------ main: one wave owns (m, 32 rows). NO LDS/barriers (R22 166us shape). ------
// ------ fp16 single-pass MFMA + top-3 float scan (R19/R21-validated guard);  ------
// ------ near-ties append {row,m,i1,i2,i3} for the tiny repair kernel.        ------
__global__ __launch_bounds__(128) void pq_mfma22(
    const float* __restrict__ emb,
    const float* __restrict__ cb,
    const unsigned short* __restrict__ wsf,
    const float* __restrict__ wsc2,
    float* __restrict__ out,
    unsigned* __restrict__ gcnt,
    uint2* __restrict__ glist,
    unsigned cap,
    int nrows,
    int rowblks)
{
    const int tid  = (int)threadIdx.x;
    const int lane = tid & 63;
    const int hib  = lane >> 5;
    const int m    = (int)blockIdx.x & 7;               // XCD-pinned subspace
    const int rb   = ((int)blockIdx.x >> 3) * 2 + (tid >> 6);
    if (rb >= rowblks) return;
    const int row0 = rb * 32;

    const unsigned short* wb = wsf + (size_t)m * 3072 * 8;
    const float* c2p = wsc2 + m * NCODE;

    // ---- x fragments (B operand, fp16): lane l = row row0+(l&31), dims hib*8+s*16+j ----
    h8 xh[6];
    {
        int r = row0 + (lane & 31);
        if (r >= nrows) r = nrows - 1;
        const float* xr = emb + (size_t)r * EMB + m * SDIM + hib * 8;
        #pragma unroll
        for (int s = 0; s < 6; ++s) {
            float4 v0 = *(const float4*)(xr + s * 16);
            float4 v1 = *(const float4*)(xr + s * 16 + 4);
            float v[8] = { v0.x, v0.y, v0.z, v0.w, v1.x, v1.y, v1.z, v1.w };
            #pragma unroll
            for (int j = 0; j < 8; ++j) xh[s][j] = (_Float16)v[j];
        }
    }

    // ---- 4 t-pairs: acc init from c2, 12 MFMA, top-3 scan (code-ascending) ----
    float b1 = 3.4e38f, b2 = 3.4e38f, b3 = 3.4e38f;
    int   i1 = 1 << 30,  i2 = 1 << 30,  i3 = 1 << 30;
    #pragma unroll 1
    for (int p = 0; p < 4; ++p) {
        const int t0 = p * 2, t1 = t0 + 1;
        f32x16 a0, a1;
        #pragma unroll
        for (int rq = 0; rq < 4; ++rq) {
            float4 q0 = *(const float4*)(c2p + t0 * 32 + rq * 8 + hib * 4);
            float4 q1 = *(const float4*)(c2p + t1 * 32 + rq * 8 + hib * 4);
            a0[rq*4+0]=q0.x; a0[rq*4+1]=q0.y; a0[rq*4+2]=q0.z; a0[rq*4+3]=q0.w;
            a1[rq*4+0]=q1.x; a1[rq*4+1]=q1.y; a1[rq*4+2]=q1.z; a1[rq*4+3]=q1.w;
        }
        __builtin_amdgcn_s_setprio(1);
        #pragma unroll
        for (int s = 0; s < 6; ++s) {
            h8 c0 = *(const h8*)(wb + (size_t)((t0 * 6 + s) * 64 + lane) * 8);
            h8 c1 = *(const h8*)(wb + (size_t)((t1 * 6 + s) * 64 + lane) * 8);
            a0 = __builtin_amdgcn_mfma_f32_32x32x16_f16(c0, xh[s], a0, 0, 0, 0);
            a1 = __builtin_amdgcn_mfma_f32_32x32x16_f16(c1, xh[s], a1, 0, 0, 0);
        }
        __builtin_amdgcn_s_setprio(0);
        // top-3 serial scan, ascending code order per lane (first-min tie rule)
        #pragma unroll
        for (int r = 0; r < 16; ++r) {
            float sv = a0[r];
            int   kv = t0 * 32 + (r & 3) + 8 * (r >> 2) + hib * 4;
            if (sv < b1)      { b3 = b2; i3 = i2; b2 = b1; i2 = i1; b1 = sv; i1 = kv; }
            else if (sv < b2) { b3 = b2; i3 = i2; b2 = sv; i2 = kv; }
            else if (sv < b3) { b3 = sv; i3 = kv; }
        }
        #pragma unroll
        for (int r = 0; r < 16; ++r) {
            float sv = a1[r];
            int   kv = t1 * 32 + (r & 3) + 8 * (r >> 2) + hib * 4;
            if (sv < b1)      { b3 = b2; i3 = i2; b2 = b1; i2 = i1; b1 = sv; i1 = kv; }
            else if (sv < b2) { b3 = b2; i3 = i2; b2 = sv; i2 = kv; }
            else if (sv < b3) { b3 = sv; i3 = kv; }
        }
    }
    {   // merge lane^32 partner's sorted triple (index-aware, R21-validated)
        float ob1 = __shfl_xor(b1, 32), ob2 = __shfl_xor(b2, 32), ob3 = __shfl_xor(b3, 32);
        int   oi1 = __shfl_xor(i1, 32), oi2 = __shfl_xor(i2, 32), oi3 = __shfl_xor(i3, 32);
        auto ins = [&](float s, int i) {
            if (s < b1 || (s == b1 && i < i1))      { b3 = b2; i3 = i2; b2 = b1; i2 = i1; b1 = s; i1 = i; }
            else if (s < b2 || (s == b2 && i < i2)) { b3 = b2; i3 = i2; b2 = s; i2 = i; }
            else if (s < b3 || (s == b3 && i < i3)) { b3 = s; i3 = i; }
        };
        ins(ob1, oi1); ins(ob2, oi2); ins(ob3, oi3);
    }

    // ---- near-tie: append {row,m,i1,i2,i3e} (exact fp64 check in pq_repair3) ----
    {
        int grow = row0 + (lane & 31);
        if (lane < 32 && grow < nrows && (b2 - b1 < THR)) {
            int i3e = (b3 - b1 < THR) ? i3 : i1;
            unsigned pos = atomicAdd(gcnt, 1u);
            if (pos < cap)
                glist[pos] = make_uint2((unsigned)grow | ((unsigned)m << 20),
                                        (unsigned)i1 | ((unsigned)i2 << 8) | ((unsigned)i3e << 16));
        }
    }

    // ---- gather + coalesced write-out (provisional for triggered rows) ----
    #pragma unroll
    for (int ii = 0; ii < 12; ++ii) {
        int Q = ii * 64 + lane;                 // 768 = 32 rows x 24 float4
        int r = Q / 24, f = Q % 24;
        int grow = row0 + r;
        int k = __shfl(i1, r);                  // winner held by lane r (<32)
        if (grow < nrows) {
            float4 v = *(const float4*)(cb + ((size_t)m * NCODE + k) * SDIM + f * 4);
            *(float4*)(out + (size_t)grow * EMB + m * SDIM + f * 4) = v;
        }
    }
}

// ------ repair3: one wave per listed row; exact fp64 distances of the 3    ------
// ------ candidates via lane-per-dim COALESCED loads + butterfly. Tiny.     ------
__global__ __launch_bounds__(256) void pq_repair3(
    const float* __restrict__ emb,
    const float* __restrict__ cb,
    float* __restrict__ out,
    const unsigned* __restrict__ gcnt,
    const uint2* __restrict__ glist,
    unsigned cap)
{
    const int tid  = (int)threadIdx.x;
    const int lane = tid & 63;
    const bool act = lane < 24;                 // 24 lanes x 4 dims = 96
    const int  dof = act ? lane * 4 : 0;
    const unsigned wv = (unsigned)blockIdx.x * 4u + (unsigned)(tid >> 6);
    unsigned n = *gcnt; if (n > cap) n = cap;

    for (unsigned j = wv; j < n; j += 4096u) {
        uint2 e = glist[j];
        int grow = (int)(e.x & 0xFFFFFu);
        int m    = (int)(e.x >> 20);
        int c1   = (int)(e.y & 0xFFu);
        int c2   = (int)((e.y >> 8) & 0xFFu);
        int c3   = (int)((e.y >> 16) & 0xFFu);
        const float* xr  = emb + (size_t)grow * EMB + m * SDIM;
        const float* cbm = cb + (size_t)m * NCODE * SDIM;

        float4 xv = act ? *(const float4*)(xr + dof) : make_float4(0.f, 0.f, 0.f, 0.f);

        auto dist = [&](int code) -> double {
            double par = 0.0;
            if (act) {
                float4 cc = *(const float4*)(cbm + (size_t)code * SDIM + dof);
                double d0 = (double)xv.x - (double)cc.x;
                double d1 = (double)xv.y - (double)cc.y;
                double d2 = (double)xv.z - (double)cc.z;
                double d3 = (double)xv.w - (double)cc.w;
                par = d0*d0 + d1*d1 + d2*d2 + d3*d3;
            }
            #pragma unroll
            for (int off = 32; off > 0; off >>= 1)
                par += __shfl_xor(par, off);    // all 64 lanes end with the total
            return par;
        };
        double d1 = dist(c1);
        double d2 = dist(c2);
        double d3 = dist(c3);

        int bi = c1; double bd = d1;            // index-aware: numpy first-min rule
        if (d2 < bd || (d2 == bd && c2 < bi)) { bd = d2; bi = c2; }
        if (d3 < bd || (d3 == bd && c3 < bi)) { bd = d3; bi = c3; }

        if (act) {
            float4 v = *(const float4*)(cbm + (size_t)bi * SDIM + dof);
            *(float4*)(out + (size_t)grow * EMB + m * SDIM + dof) = v;
        }
    }
}

// ---------------- fallback (round-2 kernel, validated) ----------------
__global__ __launch_bounds__(256) void pq_argmin_kernel(
    const float* __restrict__ emb, const float* __restrict__ cb,
    float* __restrict__ out, int nrows)
{
    const int m   = (int)(blockIdx.x & 7);
    const int row = (int)(blockIdx.x >> 3) * 256 + (int)threadIdx.x;
    const float* __restrict__ cbm = cb + (size_t)m * (NCODE * SDIM);
    __shared__ float half_c2[NCODE];
    {
        const int k = (int)threadIdx.x;
        const float* c = cbm + k * SDIM;
        float s = 0.f;
        #pragma unroll
        for (int i = 0; i < SDIM; i += 4) {
            const float4 v = *reinterpret_cast<const float4*>(c + i);
            s = fmaf(v.x, v.x, s); s = fmaf(v.y, v.y, s);
            s = fmaf(v.z, v.z, s); s = fmaf(v.w, v.w, s);
        }
        half_c2[k] = 0.5f * s;
    }
    __syncthreads();
    if (row >= nrows) return;
    float x[SDIM];
    {
        const float* xr = emb + (size_t)row * EMB + m * SDIM;
        #pragma unroll
        for (int i = 0; i < SDIM; i += 4) {
            const float4 v = *reinterpret_cast<const float4*>(xr + i);
            x[i+0] = v.x; x[i+1] = v.y; x[i+2] = v.z; x[i+3] = v.w;
        }
    }
    float best = 3.4e38f, best2 = 3.4e38f;
    int bestk = 0, bestk2 = 0;
    #pragma unroll 1
    for (int k = 0; k < NCODE; k += 4) {
        const float* c0 = cbm + (k + 0) * SDIM;
        const float* c1 = cbm + (k + 1) * SDIM;
        const float* c2 = cbm + (k + 2) * SDIM;
        const float* c3 = cbm + (k + 3) * SDIM;
        float a0 = 0.f, a1 = 0.f, a2 = 0.f, a3 = 0.f;
        #pragma unroll
        for (int i = 0; i < SDIM; i += 4) {
            const float4 v0 = *reinterpret_cast<const float4*>(c0 + i);
            const float4 v1 = *reinterpret_cast<const float4*>(c1 + i);
            const float4 v2 = *reinterpret_cast<const float4*>(c2 + i);
            const float4 v3 = *reinterpret_cast<const float4*>(c3 + i);
            a0 = fmaf(x[i+0], v0.x, a0); a0 = fmaf(x[i+1], v0.y, a0);
            a0 = fmaf(x[i+2], v0.z, a0); a0 = fmaf(x[i+3], v0.w, a0);
            a1 = fmaf(x[i+0], v1.x, a1); a1 = fmaf(x[i+1], v1.y, a1);
            a1 = fmaf(x[i+2], v1.z, a1); a1 = fmaf(x[i+3], v1.w, a1);
            a2 = fmaf(x[i+0], v2.x, a2); a2 = fmaf(x[i+1], v2.y, a2);
            a2 = fmaf(x[i+2], v2.z, a2); a2 = fmaf(x[i+3], v2.w, a2);
            a3 = fmaf(x[i+0], v3.x, a3); a3 = fmaf(x[i+1], v3.y, a3);
            a3 = fmaf(x[i+2], v3.z, a3); a3 = fmaf(x[i+3], v3.w, a3);
        }
        const float s[4] = { half_c2[k+0] - a0, half_c2[k+1] - a1,
                             half_c2[k+2] - a2, half_c2[k+3] - a3 };
        #pragma unroll
        for (int j = 0; j < 4; ++j) {
            if (s[j] < best)       { best2 = best; bestk2 = bestk; best = s[j]; bestk = k + j; }
            else if (s[j] < best2) { best2 = s[j]; bestk2 = k + j; }
        }
    }
    if (best2 - best < 0.02f) {
        const float* ca = cbm + bestk  * SDIM;
        const float* cbv = cbm + bestk2 * SDIM;
        double da = 0.0, db = 0.0;
        for (int i = 0; i < SDIM; ++i) {
            const double ea = (double)x[i] - (double)ca[i];
            const double eb = (double)x[i] - (double)cbv[i];
            da += ea * ea; db += eb * eb;
        }
        if (db < da || (db == da && bestk2 < bestk)) bestk = bestk2;
    }
    const float* cbest = cbm + bestk * SDIM;
    float* o = out + (size_t)row * EMB + m * SDIM;
    #pragma unroll
    for (int i = 0; i < SDIM; i += 4)
        *reinterpret_cast<float4*>(o + i) = *reinterpret_cast<const float4*>(cbest + i);
}

extern "C" void kernel_launch(void* const* d_in, const int* in_sizes, int n_in,
                              void* d_out, int out_size, void* d_ws, size_t ws_size,
                              hipStream_t stream) {
    const float* emb = (const float*)d_in[0];
    const float* cb  = (const float*)d_in[1];
    float* out = (float*)d_out;
    const int nrows = in_sizes[0] / EMB;    // 65536

    if (ws_size < WS_NEEDED) {
        const int rowBlocks = (nrows + 255) / 256;
        pq_argmin_kernel<<<dim3(rowBlocks * NSUB), dim3(256), 0, stream>>>(emb, cb, out, nrows);
        return;
    }

    unsigned short* wsf = (unsigned short*)d_ws;
    float*    wsc2  = (float*)((char*)d_ws + WS_FRAG_BYTES);
    unsigned* gcnt  = (unsigned*)((char*)d_ws + CNT_OFF);
    uint2*    glist = (uint2*)((char*)d_ws + LIST_OFF);
    unsigned  cap   = (unsigned)((ws_size - LIST_OFF) / 8);

    hipMemsetAsync(gcnt, 0, 4, stream);
    pq_prep_h<<<dim3(NSUB), dim3(256), 0, stream>>>(cb, wsf, wsc2);

    const int rowblks = (nrows + 31) / 32;              // 2048
    const int nb      = ((rowblks + 1) / 2) * NSUB;     // 8192 blocks of 128
    pq_mfma22<<<dim3(nb), dim3(128), 0, stream>>>(emb, cb, wsf, wsc2, out,
                                                  gcnt, glist, cap, nrows, rowblks);
    pq_repair3<<<dim3(1024), dim3(256), 0, stream>>>(emb, cb, out, gcnt, glist, cap);
}